// Round 2
// baseline (423.335 us; speedup 1.0000x reference)
//
#include <hip/hip_runtime.h>

#define NSTEPS 20
#define ALPHA  0.9f
#define VTH    1.0f
#define GSOMA  0.3f
#define ISCALE 0.5f

#define NOR  21
#define NORN 42
#define NLN  56
#define NPN  42
#define NKC  2000
#define NOD  34

#define TPB  256
#define KPER 8   // KCs per thread: 250 threads * 8 = 2000

__global__ __launch_bounds__(TPB)
void snn_kernel(const float* __restrict__ or_input,   // [B,21]
                const float* __restrict__ or_gains,   // [21]
                const float* __restrict__ mapping,    // [21,42]
                const float* __restrict__ orn_to_pn,  // [42,42]
                const float* __restrict__ orn_to_ln,  // [42,56]
                const float* __restrict__ ln_to_pn,   // [56,42]
                const float* __restrict__ pn_to_kc,   // [42,2000]
                const float* __restrict__ kc_to_apl,  // [2000,1]
                const float* __restrict__ apl_to_kc,  // [1,2000]
                const float* __restrict__ dec_w,      // [2000,34]
                const float* __restrict__ dec_b,      // [34]
                float* __restrict__ out)              // [B,34]
{
    __shared__ float sW_ol[NORN * NLN];   // orn_to_ln
    __shared__ float sW_op[NORN * NPN];   // orn_to_pn
    __shared__ float sW_lp[NLN * NPN];    // ln_to_pn
    __shared__ float sSpg[NOR];
    __shared__ float sRed[4];
    __shared__ float sRed2[4 * NOD];
    __shared__ unsigned long long sMask;  // PN spike bitmask

    const int tid  = threadIdx.x;
    const int lane = tid & 63;
    const int wid  = tid >> 6;
    const int b    = blockIdx.x;

    // ---- stage small weights into LDS ----
    for (int i = tid; i < NORN * NLN; i += TPB) sW_ol[i] = orn_to_ln[i];
    for (int i = tid; i < NORN * NPN; i += TPB) sW_op[i] = orn_to_pn[i];
    for (int i = tid; i < NLN * NPN;  i += TPB) sW_lp[i] = ln_to_pn[i];
    if (tid < NOR) sSpg[tid] = log1pf(expf(or_gains[tid]));  // softplus
    if (tid < 4)   sRed[tid] = 0.f;
    __syncthreads();

    // ---- wave 0, lane<42: this lane's ORN drive (I_SCALE * (x*spg)@mapping) ----
    float drive = 0.f;
    if (wid == 0 && lane < NORN) {
        const float* x = or_input + (long)b * NOR;
        for (int i = 0; i < NOR; ++i) drive += x[i] * sSpg[i] * mapping[i * NORN + lane];
        drive *= ISCALE;
    }

    // ---- per-thread KC state (8 contiguous KCs) ----
    const int  kbase = tid * KPER;
    const bool act   = (kbase < NKC);   // tid < 250
    float vd[KPER], va[KPER], cnt[KPER], wa2k[KPER], wk2a[KPER];
#pragma unroll
    for (int j = 0; j < KPER; ++j) {
        vd[j] = 0.f; va[j] = 0.f; cnt[j] = 0.f;
        wa2k[j] = act ? apl_to_kc[kbase + j] : 0.f;
        wk2a[j] = act ? kc_to_apl[kbase + j] : 0.f;
    }
    float v_orn = 0.f, v_ln = 0.f, v_pn = 0.f;
    __syncthreads();

    // ================= time loop (2 barriers/step) =================
    for (int t = 0; t < NSTEPS; ++t) {
        // APL from previous step's partials (all threads, redundant)
        const float apl = fmaxf(sRed[0] + sRed[1] + sRed[2] + sRed[3], 0.f);

        // --- wave 0: ORN -> LN -> PN chain via ballot spike masks ---
        if (wid == 0) {
            bool s = false;
            if (lane < NORN) {
                v_orn = ALPHA * v_orn + drive;
                s = (v_orn - VTH) > 0.f;
                if (s) v_orn = 0.f;
            }
            unsigned long long mOrn = __ballot(s);

            bool sl = false;
            if (lane < NLN) {
                float a = 0.f;
                for (int o = 0; o < NORN; ++o)
                    if ((mOrn >> o) & 1ULL) a += sW_ol[o * NLN + lane];
                v_ln = ALPHA * v_ln + a;
                sl = (v_ln - VTH) > 0.f;
                if (sl) v_ln = 0.f;
            }
            unsigned long long mLn = __ballot(sl);

            bool sp = false;
            if (lane < NPN) {
                float e = 0.f;
                for (int o = 0; o < NORN; ++o)
                    if ((mOrn >> o) & 1ULL) e += sW_op[o * NPN + lane];
                float h = 0.f;
                for (int l = 0; l < NLN; ++l)
                    if ((mLn >> l) & 1ULL) h += sW_lp[l * NPN + lane];
                v_pn = ALPHA * v_pn + e - h;
                sp = (v_pn - VTH) > 0.f;
                if (sp) v_pn = 0.f;
            }
            unsigned long long mPn = __ballot(sp);
            if (lane == 0) sMask = mPn;
        }

        // --- all waves: KC dendrite decay + APL inhibition ---
#pragma unroll
        for (int j = 0; j < KPER; ++j) vd[j] = ALPHA * vd[j] - apl * wa2k[j];

        __syncthreads();   // barrier 1: sMask visible; top-of-loop sRed reads done

        // --- KC gather over spiking PNs, 4 rows per batch for MLP ---
        {
            unsigned long long m = sMask;
            while (m) {
                int p0 = __builtin_ctzll(m); m &= m - 1;
                int p1 = 0, p2 = 0, p3 = 0;
                float f1 = 0.f, f2 = 0.f, f3 = 0.f;
                if (m) { p1 = __builtin_ctzll(m); m &= m - 1; f1 = 1.f; }
                if (m) { p2 = __builtin_ctzll(m); m &= m - 1; f2 = 1.f; }
                if (m) { p3 = __builtin_ctzll(m); m &= m - 1; f3 = 1.f; }
                if (act) {
                    const float4* w0 = (const float4*)(pn_to_kc + (long)p0 * NKC + kbase);
                    const float4* w1 = (const float4*)(pn_to_kc + (long)p1 * NKC + kbase);
                    const float4* w2 = (const float4*)(pn_to_kc + (long)p2 * NKC + kbase);
                    const float4* w3 = (const float4*)(pn_to_kc + (long)p3 * NKC + kbase);
                    float4 a0 = w0[0], a1 = w0[1];
                    float4 b0 = w1[0], b1 = w1[1];
                    float4 c0 = w2[0], c1 = w2[1];
                    float4 d0 = w3[0], d1 = w3[1];
                    vd[0] += a0.x + f1 * b0.x + f2 * c0.x + f3 * d0.x;
                    vd[1] += a0.y + f1 * b0.y + f2 * c0.y + f3 * d0.y;
                    vd[2] += a0.z + f1 * b0.z + f2 * c0.z + f3 * d0.z;
                    vd[3] += a0.w + f1 * b0.w + f2 * c0.w + f3 * d0.w;
                    vd[4] += a1.x + f1 * b1.x + f2 * c1.x + f3 * d1.x;
                    vd[5] += a1.y + f1 * b1.y + f2 * c1.y + f3 * d1.y;
                    vd[6] += a1.z + f1 * b1.z + f2 * c1.z + f3 * d1.z;
                    vd[7] += a1.w + f1 * b1.w + f2 * c1.w + f3 * d1.w;
                }
            }
        }

        // --- KC soma, spike, count, APL partial ---
        {
            float aplp = 0.f;
#pragma unroll
            for (int j = 0; j < KPER; ++j) {
                va[j] = ALPHA * va[j] + GSOMA * (vd[j] - va[j]);
                float s = (va[j] - VTH) > 0.f ? 1.f : 0.f;
                va[j] *= (1.f - s);
                cnt[j] += s;
                aplp += s * wk2a[j];
            }
            for (int off = 32; off > 0; off >>= 1) aplp += __shfl_xor(aplp, off, 64);
            if (lane == 0) sRed[wid] = aplp;
        }
        __syncthreads();   // barrier 2: sRed visible for next step; sMask consumed
    }

    // ================= epilogue: logits = (cnt/20) @ dec_w + dec_b =================
    float acc[NOD];
#pragma unroll
    for (int o = 0; o < NOD; ++o) acc[o] = 0.f;
    if (act) {
#pragma unroll
        for (int j = 0; j < KPER; ++j) {
            float r = cnt[j] / 20.0f;
            if (r != 0.f) {                       // KC sparsity: skip silent KCs
                const float* wr = dec_w + (long)(kbase + j) * NOD;
#pragma unroll
                for (int o = 0; o < NOD; ++o) acc[o] += r * wr[o];
            }
        }
    }
#pragma unroll
    for (int o = 0; o < NOD; ++o) {
        float v = acc[o];
        for (int off = 32; off > 0; off >>= 1) v += __shfl_xor(v, off, 64);
        if ((tid & 63) == 0) sRed2[(tid >> 6) * NOD + o] = v;
    }
    __syncthreads();
    if (tid < NOD) {
        float v = sRed2[tid] + sRed2[NOD + tid] + sRed2[2 * NOD + tid] +
                  sRed2[3 * NOD + tid] + dec_b[tid];
        out[(long)b * NOD + tid] = v;
    }
}

extern "C" void kernel_launch(void* const* d_in, const int* in_sizes, int n_in,
                              void* d_out, int out_size, void* d_ws, size_t ws_size,
                              hipStream_t stream) {
    (void)n_in; (void)out_size; (void)d_ws; (void)ws_size;
    const float* or_input  = (const float*)d_in[0];
    const float* or_gains  = (const float*)d_in[1];
    const float* mapping   = (const float*)d_in[2];
    const float* orn_to_pn = (const float*)d_in[3];
    const float* orn_to_ln = (const float*)d_in[4];
    const float* ln_to_pn  = (const float*)d_in[5];
    const float* pn_to_kc  = (const float*)d_in[6];
    const float* kc_to_apl = (const float*)d_in[7];
    const float* apl_to_kc = (const float*)d_in[8];
    const float* dec_w     = (const float*)d_in[9];
    const float* dec_b     = (const float*)d_in[10];
    float* out = (float*)d_out;

    const int batch = in_sizes[0] / NOR;  // 4096
    hipLaunchKernelGGL(snn_kernel, dim3(batch), dim3(TPB), 0, stream,
                       or_input, or_gains, mapping, orn_to_pn, orn_to_ln,
                       ln_to_pn, pn_to_kc, kc_to_apl, apl_to_kc, dec_w, dec_b, out);
}